// Round 1
// 2902.841 us; speedup vs baseline: 1.3213x; 1.3213x over previous
//
#include <hip/hip_runtime.h>
#include <hip/hip_bf16.h>

#define NH 32
#define NKV 8
#define HD 128
#define HIDDEN 4096
#define QS 4096
#define ECOLS 6144
#define SEQ 2048
#define ATT_SCALE 0.08838834764831845f

typedef __attribute__((ext_vector_type(8))) short short8;
typedef __attribute__((ext_vector_type(4))) float f32x4;
typedef __hip_bfloat16 bf16;

__device__ inline f32x4 mfma_bf(short8 a, short8 b, f32x4 c) {
  return __builtin_amdgcn_mfma_f32_16x16x32_bf16(a, b, c, 0, 0, 0);
}

__device__ inline float bfbits_to_f(unsigned short u) {
  unsigned int x = ((unsigned int)u) << 16;
  float f;
  __builtin_memcpy(&f, &x, 4);
  return f;
}

__device__ inline short f_to_bfbits(float f) {
  unsigned int x;
  __builtin_memcpy(&x, &f, 4);
  unsigned int r = (x + 0x7FFFu + ((x >> 16) & 1u)) >> 16;
  return (short)r;
}

// Deterministic per-block dtype probe: weights have |x|<0.1 as true bf16;
// f32 data read as bf16 shorts contains |x|>1 or NaN almost surely.
__device__ inline bool detect_f32(const void* weight_base) {
  const unsigned short* p = (const unsigned short*)weight_base;
  bool f32m = false;
  for (int i = 0; i < 128; ++i) {
    float v = fabsf(bfbits_to_f(p[i]));
    if (!(v <= 1.0f)) f32m = true;  // catches big AND NaN
  }
  return f32m;
}

// Load 8 contiguous elements starting at element index `idx` from `base`,
// returning bf16 bits. f32m selects fp32->bf16 convert path.
__device__ inline short8 ld8(const void* base, size_t idx, bool f32m) {
  if (!f32m) return *(const short8*)((const short*)base + idx);
  const float* p = (const float*)base + idx;
  float4 a = *(const float4*)p;
  float4 b = *(const float4*)(p + 4);
  short8 r;
  r[0] = f_to_bfbits(a.x); r[1] = f_to_bfbits(a.y);
  r[2] = f_to_bfbits(a.z); r[3] = f_to_bfbits(a.w);
  r[4] = f_to_bfbits(b.x); r[5] = f_to_bfbits(b.y);
  r[6] = f_to_bfbits(b.z); r[7] = f_to_bfbits(b.w);
  return r;
}

// ---------------- diagnostic fill -----------------------------------------
__global__ __launch_bounds__(256) void fill_out(bf16* __restrict__ out, int n, float v) {
  int i = blockIdx.x * 256 + threadIdx.x;
  if (i < n) out[i] = __float2bfloat16(v);
}

// ---------------- GEMM: C = A[.][K] * B[K][N] ------------------------------
// A at element offset a_off, row stride K. B at b_off, row stride ldb (always
// external dtype). C at c_off, stride ldc.
// flags: bit0 trans_c, bit1 a_ext (A in external dtype), bit2 c_ext (C to
// external dtype). nan_fill: substituted for non-finite acc (diagnostic).
__global__ __launch_bounds__(256) void gemm_bn(const void* __restrict__ A, size_t a_off,
                                               const void* __restrict__ B, size_t b_off,
                                               void* __restrict__ C, size_t c_off,
                                               int K, int ldb, int ldc, int flags,
                                               float nan_fill) {
  __shared__ __align__(16) short sA[128 * 32];
  __shared__ __align__(16) short sBT[128 * 40];  // [n][k], stride 40
  const bool f32m = detect_f32(B);
  const bool a_f32 = f32m && (flags & 2);
  const int tid = threadIdx.x;
  const int lane = tid & 63, wv = tid >> 6;
  const int quad = lane >> 4, l16 = lane & 15;
  const int row0 = blockIdx.y * 128, col0 = blockIdx.x * 128;
  const int wr = wv >> 1, wc = wv & 1;
  const int srow = tid >> 2;        // 0..63
  const int scol = (tid & 3) * 8;   // 0,8,16,24
  const int kr = tid >> 3;          // 0..31
  const int nv = (tid & 7) * 8;     // 0,8,..,56

  f32x4 acc[4][4] = {};

  for (int k0 = 0; k0 < K; k0 += 32) {
    short8 a0 = ld8(A, a_off + (size_t)(row0 + srow) * K + k0 + scol, a_f32);
    short8 a1 = ld8(A, a_off + (size_t)(row0 + 64 + srow) * K + k0 + scol, a_f32);
    short8 b0 = ld8(B, b_off + (size_t)(k0 + kr) * ldb + col0 + nv, f32m);
    short8 b1 = ld8(B, b_off + (size_t)(k0 + kr) * ldb + col0 + 64 + nv, f32m);
    __syncthreads();  // previous iteration's fragment reads complete
    *(short8*)&sA[srow * 32 + scol] = a0;
    *(short8*)&sA[(64 + srow) * 32 + scol] = a1;
    #pragma unroll
    for (int j = 0; j < 8; ++j) {
      sBT[(nv + j) * 40 + kr] = b0[j];
      sBT[(64 + nv + j) * 40 + kr] = b1[j];
    }
    __syncthreads();
    short8 aF[4], bF[4];
    #pragma unroll
    for (int i = 0; i < 4; ++i) {
      aF[i] = *(const short8*)&sA[(wr * 64 + i * 16 + l16) * 32 + quad * 8];
      bF[i] = *(const short8*)&sBT[(wc * 64 + i * 16 + l16) * 40 + quad * 8];
    }
    #pragma unroll
    for (int mi = 0; mi < 4; ++mi)
      #pragma unroll
      for (int ni = 0; ni < 4; ++ni)
        acc[mi][ni] = mfma_bf(aF[mi], bF[ni], acc[mi][ni]);
  }

  const bool c_f32 = f32m && (flags & 4);
  #pragma unroll
  for (int mi = 0; mi < 4; ++mi)
    #pragma unroll
    for (int ni = 0; ni < 4; ++ni) {
      int col = col0 + wc * 64 + ni * 16 + l16;
      #pragma unroll
      for (int r = 0; r < 4; ++r) {
        int row = row0 + wr * 64 + mi * 16 + quad * 4 + r;
        size_t idx = c_off + ((flags & 1) ? (size_t)col * ldc + row
                                         : (size_t)row * ldc + col);
        float x = acc[mi][ni][r];
        x = __builtin_isfinite(x) ? x : nan_fill;
        if (c_f32) ((float*)C)[idx] = x;
        else ((bf16*)C)[idx] = __float2bfloat16(x);
      }
    }
}

// ---------------- RoPE in place (internal bf16 buffers) --------------------
__global__ __launch_bounds__(256) void rope_rows(bf16* __restrict__ x,
                                                 const int* __restrict__ pos,
                                                 int n_heads, int ld) {
  const int s = blockIdx.x;
  const float p = (float)pos[s];
  bf16* row = x + (size_t)s * ld;
  const float NLN = -0.14391156831212787f;  // -ln(10000)/64
  const int total = n_heads * 64;
  for (int t = threadIdx.x; t < total; t += 256) {
    int h = t >> 6, d = t & 63;
    bf16* base = row + h * HD;
    float ang = p * __expf((float)d * NLN);
    float cs = cosf(ang), sn = sinf(ang);
    float x1 = __bfloat162float(base[d]);
    float x2 = __bfloat162float(base[d + 64]);
    base[d] = __float2bfloat16(x1 * cs - x2 * sn);
    base[d + 64] = __float2bfloat16(x2 * cs + x1 * sn);
  }
}

// ---------------- flash attention on a q-chunk (internal bf16) -------------
// 2-phase double-buffered rewrite:
//  - KVBLK=64 (halves softmax/shuffle rounds per kv element)
//  - K[64][128] and V^T[128][64] tiles staged in LDS per block, shared by the
//    4 waves, loaded async via global_load_lds width-16, double-buffered:
//    tile t+1 issued at top of round t, drained by the single end-of-round
//    __syncthreads (which waits vmcnt(0)).
//  - LDS tiles XOR-swizzled: global_load_lds writes linearly, so the global
//    SOURCE per-lane addresses are pre-swizzled (chunk16 ^= row&7) and reads
//    apply the same XOR -> ds_read_b128 at the conflict-free floor.
//  - P exchange is wave-private: no barrier, just lgkmcnt(0)+sched_barrier.
//  - heavy-first block order (qt descending) for load balance.
__global__ __launch_bounds__(256) void attn_fwd(const short* __restrict__ q_c,
                                                const short* __restrict__ k_b,
                                                const short* __restrict__ Vt_b,
                                                bf16* __restrict__ O_c,
                                                int q_glob_base, int n_qt) {
  __shared__ __align__(16) short sK[2][64 * 128];   // 16 KB each, swizzled
  __shared__ __align__(16) short sV[2][128 * 64];   // 16 KB each, swizzled
  __shared__ __align__(16) short pl[4][16 * 64];    // per-wave P tile, 2 KB

  const int tid = threadIdx.x;
  const int lane = tid & 63, w = tid >> 6;
  const int quad = lane >> 4, l16 = lane & 15;
  const int h = blockIdx.x % NH;
  const int qt = n_qt - 1 - blockIdx.x / NH;  // heavy-first dispatch order
  const int kh = h >> 2;
  const int q0l = qt * 64 + w * 16;
  const int q0g_blk = q_glob_base + qt * 64;
  const int nR = (q0g_blk >> 6) + 1;  // number of 64-wide kv rounds

  const char* kbase = (const char*)(k_b + kh * HD);              // row stride 2048 B
  const char* vtb = (const char*)(Vt_b + (size_t)kh * HD * SEQ); // row stride 4096 B

  // Async stage of kv tile tt into buffer buf. Waves 0,1: K rows (4 rows /
  // 1KB instr); waves 2,3: V^T rows (8 rows / 1KB instr). LDS dest linear,
  // global source pre-swizzled (16B chunk index ^= row&7).
  auto stage = [&](int tt, int buf) {
    const int kv0s = tt * 64;
    if (w < 2) {
      #pragma unroll
      for (int i = 0; i < 8; ++i) {
        const int rb = (w * 8 + i) * 4;
        const int rl = rb + (lane >> 4);
        const int pos = lane & 15;
        const char* src = kbase + (size_t)(kv0s + rl) * 2048 + ((pos ^ (rl & 7)) << 4);
        __builtin_amdgcn_global_load_lds(
            (const __attribute__((address_space(1))) void*)src,
            (__attribute__((address_space(3))) void*)&sK[buf][rb * 128], 16, 0, 0);
      }
    } else {
      #pragma unroll
      for (int i = 0; i < 8; ++i) {
        const int rb = ((w - 2) * 8 + i) * 8;
        const int rl = rb + (lane >> 3);
        const int pos = lane & 7;
        const char* src = vtb + (size_t)rl * 4096 + (size_t)kv0s * 2 + ((pos ^ (rl & 7)) << 4);
        __builtin_amdgcn_global_load_lds(
            (const __attribute__((address_space(1))) void*)src,
            (__attribute__((address_space(3))) void*)&sV[buf][rb * 64], 16, 0, 0);
      }
    }
  };

  short8 qF[4];
  #pragma unroll
  for (int ks = 0; ks < 4; ++ks)
    qF[ks] = *(const short8*)(q_c + (size_t)(q0l + l16) * QS + h * HD +
                              ks * 32 + quad * 8);

  f32x4 o[8];
  float mi[4], li[4];
  #pragma unroll
  for (int nt = 0; nt < 8; ++nt) o[nt] = f32x4{0.f, 0.f, 0.f, 0.f};
  #pragma unroll
  for (int r = 0; r < 4; ++r) { mi[r] = -1e30f; li[r] = 0.f; }

  stage(0, 0);
  __syncthreads();  // drains vmcnt(0): tile 0 resident for all waves

  for (int t = 0; t < nR; ++t) {
    const int cur = t & 1;
    if (t + 1 < nR) stage(t + 1, cur ^ 1);  // prefetch hides under this round
    const short* sKc = &sK[cur][0];
    const short* sVc = &sV[cur][0];
    const bool last = (t == nR - 1);

    // ---- QK^T over 64 kv cols: s[g] covers cols g*16+l16 ----
    f32x4 s[4] = {f32x4{0.f, 0.f, 0.f, 0.f}, f32x4{0.f, 0.f, 0.f, 0.f},
                  f32x4{0.f, 0.f, 0.f, 0.f}, f32x4{0.f, 0.f, 0.f, 0.f}};
    #pragma unroll
    for (int ks = 0; ks < 4; ++ks) {
      #pragma unroll
      for (int g = 0; g < 4; ++g) {
        short8 kf = *(const short8*)&sKc[(g * 16 + l16) * 128 +
                                         (((ks * 4 + quad) ^ (l16 & 7)) << 3)];
        s[g] = mfma_bf(qF[ks], kf, s[g]);
      }
    }

    // ---- online softmax over the 64 cols ----
    float alpha[4];
    #pragma unroll
    for (int r = 0; r < 4; ++r) {
      float v[4];
      #pragma unroll
      for (int g = 0; g < 4; ++g) {
        float x = s[g][r] * ATT_SCALE;
        if (last && (g * 16 + l16 > w * 16 + quad * 4 + r)) x = -1e30f;
        v[g] = x;
      }
      float tm = fmaxf(fmaxf(v[0], v[1]), fmaxf(v[2], v[3]));
      #pragma unroll
      for (int off = 1; off < 16; off <<= 1) tm = fmaxf(tm, __shfl_xor(tm, off, 64));
      float mn = fmaxf(mi[r], tm);
      alpha[r] = __expf(mi[r] - mn);
      const int ro = quad * 4 + r;
      const int key = ro >> 1;  // P swizzle key (row>>1)&7, ro<16
      float rs = 0.f;
      #pragma unroll
      for (int g = 0; g < 4; ++g) {
        float pg = __expf(v[g] - mn);
        rs += pg;
        pl[w][ro * 64 + (((g * 2 + (l16 >> 3)) ^ key) << 3) + (l16 & 7)] =
            f_to_bfbits(pg);
      }
      #pragma unroll
      for (int off = 1; off < 16; off <<= 1) rs += __shfl_xor(rs, off, 64);
      li[r] = li[r] * alpha[r] + rs;
      mi[r] = mn;
    }

    // Wave-private P exchange: order cross-lane LDS write->read without a
    // block barrier (compiler can't see the cross-lane dep -> explicit wait).
    asm volatile("s_waitcnt lgkmcnt(0)" ::: "memory");
    __builtin_amdgcn_sched_barrier(0);
    const int pkey = l16 >> 1;
    short8 pa0 = *(const short8*)&pl[w][l16 * 64 + ((quad ^ pkey) << 3)];
    short8 pa1 = *(const short8*)&pl[w][l16 * 64 + (((4 + quad) ^ pkey) << 3)];

    #pragma unroll
    for (int nt = 0; nt < 8; ++nt) {
      #pragma unroll
      for (int r = 0; r < 4; ++r) o[nt][r] *= alpha[r];
    }

    // ---- PV over the 64 kv cols (two 32-wide k-slices) ----
    const int vkey = l16 & 7;
    #pragma unroll
    for (int nt = 0; nt < 8; ++nt) {
      short8 vf0 = *(const short8*)&sVc[(nt * 16 + l16) * 64 + ((quad ^ vkey) << 3)];
      short8 vf1 = *(const short8*)&sVc[(nt * 16 + l16) * 64 + (((4 + quad) ^ vkey) << 3)];
      o[nt] = mfma_bf(pa0, vf0, o[nt]);
      o[nt] = mfma_bf(pa1, vf1, o[nt]);
    }

    // One barrier per round: waits own vmcnt(0) (prefetch t+1 resident) and
    // lgkmcnt(0) (all waves done reading buf[cur] before it is re-staged).
    if (t + 1 < nR) __syncthreads();
  }

  #pragma unroll
  for (int r = 0; r < 4; ++r) {
    float inv = 1.0f / li[r];
    int row = q0l + quad * 4 + r;
    #pragma unroll
    for (int nt = 0; nt < 8; ++nt) {
      float x = o[nt][r] * inv;
      x = __builtin_isfinite(x) ? x : 0.0f;
      O_c[(size_t)row * QS + h * HD + nt * 16 + l16] = __float2bfloat16(x);
    }
  }
}

// ---------------- workspace: k_b 4MB | Vt_b 4MB | q_c | O_c ----------------
// chunk=2048 -> 41,943,040 B; 1024 -> 25,165,824; 512 -> 16,777,216.

extern "C" void kernel_launch(void* const* d_in, const int* in_sizes, int n_in,
                              void* d_out, int out_size, void* d_ws, size_t ws_size,
                              hipStream_t stream) {
  const int* positions = (const int*)d_in[0];
  const void* hidden = d_in[1];
  const void* Wqkv = d_in[2];
  const void* Wo = d_in[3];
  char* ws = (char*)d_ws;

  int chunk;
  if (ws_size >= 41943040ULL) chunk = 2048;
  else if (ws_size >= 25165824ULL) chunk = 1024;
  else if (ws_size >= 16777216ULL) chunk = 512;
  else {
    fill_out<<<(out_size + 255) / 256, 256, 0, stream>>>(
        (bf16*)d_out, out_size, 512.0f + (float)(ws_size >> 20));
    return;
  }

  short* k_b = (short*)(ws + 0);                       // [2048][1024] bf16
  short* Vt_b = (short*)(ws + 4194304);                // [1024][2048] bf16
  short* q_c = (short*)(ws + 8388608);                 // [chunk][4096] bf16
  short* O_c = (short*)(ws + 8388608 + (size_t)chunk * 8192);

  const int n_qc = SEQ / chunk;

  for (int b = 0; b < 2; ++b) {
    const size_t hid_off = (size_t)b * SEQ * HIDDEN;
    const int* pos_b = positions + b * SEQ;

    // K projection: Wqkv cols [4096,5120) -> k_b [2048][1024]
    gemm_bn<<<dim3(8, 16), 256, 0, stream>>>(hidden, hid_off, Wqkv, 4096,
                                             k_b, 0, HIDDEN, ECOLS, 1024,
                                             /*a_ext*/ 2, 111.0f);
    // V projection, transposed write: cols [5120,6144) -> Vt_b [1024][2048]
    gemm_bn<<<dim3(8, 16), 256, 0, stream>>>(hidden, hid_off, Wqkv, 5120,
                                             Vt_b, 0, HIDDEN, ECOLS, SEQ,
                                             /*trans_c|a_ext*/ 3, 111.0f);
    // RoPE on K (8 heads)
    rope_rows<<<SEQ, 256, 0, stream>>>((bf16*)k_b, pos_b, NKV, 1024);

    for (int qc = 0; qc < n_qc; ++qc) {
      const size_t hid_c_off = hid_off + (size_t)qc * chunk * HIDDEN;
      // Q projection chunk: cols [0,4096) -> q_c [chunk][4096]
      gemm_bn<<<dim3(32, chunk / 128), 256, 0, stream>>>(
          hidden, hid_c_off, Wqkv, 0, q_c, 0, HIDDEN, ECOLS, QS,
          /*a_ext*/ 2, 111.0f);
      // RoPE on Q (32 heads)
      rope_rows<<<chunk, 256, 0, stream>>>((bf16*)q_c, pos_b + qc * chunk, NH, QS);
      // Attention chunk
      attn_fwd<<<NH * (chunk / 64), 256, 0, stream>>>(
          q_c, k_b, Vt_b, (bf16*)O_c, qc * chunk, chunk / 64);
      // O projection chunk -> out rows (external dtype)
      gemm_bn<<<dim3(32, chunk / 128), 256, 0, stream>>>(
          O_c, 0, Wo, 0, d_out, ((size_t)b * SEQ + (size_t)qc * chunk) * HIDDEN,
          QS, HIDDEN, HIDDEN, /*c_ext*/ 4, 333.0f);
    }
  }
}